// Round 1
// 2120.499 us; speedup vs baseline: 1.0993x; 1.0993x over previous
//
#include <hip/hip_runtime.h>
#include <cstdint>
#include <cstddef>

// Problem constants
#define MB_   8192            // batch
#define NPX   2048            // masked features
#define NAX   256             // addon
#define NCX   32              // covariates
#define NOX   20000           // output features
#define KTOT  2336            // 2048+256+32
#define KP    2368            // K padded to multiple of 64 (37 tiles)
#define NPAD  20096           // N rows materialized in wct (314*64)
#define NT    37              // K tiles (KP/64)
#define MTIL  32              // 8192/256
#define NTIL  79              // ceil(20000/256) -> 20224 logical cols

typedef __bf16 bf16;
typedef bf16  bf16x8 __attribute__((ext_vector_type(8)));
typedef float f32x4  __attribute__((ext_vector_type(4)));

__device__ __forceinline__ uint16_t f2bf(float f) {
  union { float f; uint32_t u; } v; v.f = f;
  uint32_t u = v.u;
  return (uint16_t)((u + 0x7FFFu + ((u >> 16) & 1u)) >> 16);  // RNE
}

__device__ __forceinline__ void gl_lds16(const void* g, void* l) {
  __builtin_amdgcn_global_load_lds(
      (const __attribute__((address_space(1))) void*)g,
      (__attribute__((address_space(3))) void*)l,
      16, 0, 0);
}

// ---------------------------------------------------------------------------
// Pre-pass 1: zc[m][k] = bf16( k<2304 ? z[m][k] : (k<2336 ? cat[m][k-2304] : 0) )
// ---------------------------------------------------------------------------
__global__ __launch_bounds__(256) void build_zc(
    const float* __restrict__ z, const float* __restrict__ cat,
    uint4* __restrict__ zc)
{
  int t = blockIdx.x * 256 + threadIdx.x;     // exactly 8192*296 threads
  int m = t / 296, kb = t % 296;
  union { uint16_t u[8]; uint4 v; } U;
  if (kb < 288) {
    const float* p = z + (size_t)m * (NPX + NAX) + kb * 8;
    #pragma unroll
    for (int j = 0; j < 8; ++j) U.u[j] = f2bf(p[j]);
  } else if (kb < 292) {
    const float* p = cat + (size_t)m * NCX + (kb - 288) * 8;
    #pragma unroll
    for (int j = 0; j < 8; ++j) U.u[j] = f2bf(p[j]);
  } else {
    #pragma unroll
    for (int j = 0; j < 8; ++j) U.u[j] = 0;
  }
  zc[t] = U.v;
}

// ---------------------------------------------------------------------------
// Pre-pass 2: WcT[n][k] = bf16 of combined weight, transposed via LDS tiles.
// ---------------------------------------------------------------------------
__device__ __forceinline__ float wval(int k, int n,
    const float* __restrict__ Wm, const float* __restrict__ Mk,
    const float* __restrict__ Wa, const float* __restrict__ Am,
    const float* __restrict__ Wc)
{
  if (k < NPX)        return Wm[(size_t)k * NOX + n] * Mk[(size_t)k * NOX + n];
  if (k < NPX + NAX)  { int kk = k - NPX;       return Wa[(size_t)kk * NOX + n] * Am[(size_t)kk * NOX + n]; }
  if (k < KTOT)       { int kk = k - NPX - NAX; return Wc[(size_t)kk * NOX + n]; }
  return 0.f;
}

__global__ __launch_bounds__(256) void build_wct(
    const float* __restrict__ Wm, const float* __restrict__ Mk,
    const float* __restrict__ Wa, const float* __restrict__ Am,
    const float* __restrict__ Wc, uint16_t* __restrict__ wct)
{
  __shared__ float tile[64][65];
  const int n0 = blockIdx.x * 64;   // 314 tiles (NPAD/64)
  const int k0 = blockIdx.y * 64;   // 37 tiles  (KP/64)
  const int t = threadIdx.x;
  {
    const int nl = t & 63, kl0 = t >> 6;
    #pragma unroll
    for (int p = 0; p < 16; ++p) {
      int kl = p * 4 + kl0;
      int k = k0 + kl, n = n0 + nl;
      float v = 0.f;
      if (n < NOX) v = wval(k, n, Wm, Mk, Wa, Am, Wc);
      tile[kl][nl] = v;
    }
  }
  __syncthreads();
  {
    const int kl = t & 63, nl0 = t >> 6;
    #pragma unroll
    for (int p = 0; p < 16; ++p) {
      int nl = p * 4 + nl0;
      int n = n0 + nl;                       // n < 20096 always
      wct[(size_t)n * KP + k0 + kl] = f2bf(tile[kl][nl]);
    }
  }
}

// ---------------------------------------------------------------------------
// GEMM, 256x256 tile / BK=64 / 8 waves (2M x 4N) / 8-phase schedule.
//   T1 XCD-chunked block swizzle, T2 (row&7) chunk-XOR LDS swizzle
//   (linear LDS dest + inverse-swizzled global source + swizzled ds_read),
//   T3+T4 4 phases per K-tile with counted vmcnt(6) once per tile,
//   T5 setprio around MFMA clusters.
// Staging units per K-tile (16 KB each, 2 gl_lds16 per thread):
//   U1 = A rows {0-63,128-191}   (read in phase 1)
//   U2 = B rows {q*64+[0,32)}    (read in phase 1)
//   U3 = A rows {64-127,192-255} (read in phase 3)
//   U4 = B rows {q*64+[32,64)}   (read in phase 2)
// Issue schedule: prologue U1..U4(0),U1..U3(1); steady state during tile t:
//   ph1: U4(t+1) -> buf^1 ; ph2: U1(t+2) -> buf ; ph3: U2(t+2) ; ph4: U3(t+2)
//   then vmcnt(6) guarantees everything through U4(t+1) landed.
// ---------------------------------------------------------------------------
__device__ __forceinline__ int umap(int mode, int idx) {
  if (mode == 0) return idx + (idx & 64);            // A-low
  if (mode == 1) return 64 + idx + (idx & 64);       // A-high
  if (mode == 2) return ((idx >> 5) << 6) | (idx & 31);        // B-low
  return ((idx >> 5) << 6) | 32 | (idx & 31);                  // B-high
}

template <int MODE>
__device__ __forceinline__ void stage_unit(
    const uint16_t* __restrict__ G, int grow0, int kb, bf16* ldsbase,
    int w, int lane, int rmax)
{
  const int cswz = (((lane & 7) ^ (lane >> 3)) << 3);   // inverse-swizzled source chunk
  #pragma unroll
  for (int l = 0; l < 2; ++l) {
    const int idx0 = (w * 2 + l) * 8;
    const int r0 = umap(MODE, idx0);                    // wave-uniform LDS row base
    int gr = grow0 + r0 + (lane >> 3);
    if (gr > rmax) gr = rmax;                           // clamp (pad rows, discarded later)
    gl_lds16(G + ((size_t)gr * KP + kb + cswz), ldsbase + r0 * 64);
  }
}

__device__ __forceinline__ bf16x8 ldsread(const bf16* base, int row, int ck) {
  // logical (row, chunk ck) lives at storage chunk ck ^ (row&7)
  return *(const bf16x8*)&base[row * 64 + ((ck ^ (row & 7)) << 3)];
}

template <int QI, int QJ>
__device__ __forceinline__ void phase_mfma(f32x4 (&acc)[8][4],
    const bf16x8 (&av)[4][2], const bf16x8 (&bv)[4][2])
{
  __builtin_amdgcn_s_barrier();
  asm volatile("s_waitcnt lgkmcnt(0)" ::: "memory");
  __builtin_amdgcn_s_setprio(1);
  #pragma unroll
  for (int ks = 0; ks < 2; ++ks)
    #pragma unroll
    for (int ii = 0; ii < 4; ++ii)
      #pragma unroll
      for (int jj = 0; jj < 2; ++jj)
        acc[QI * 4 + ii][QJ * 2 + jj] = __builtin_amdgcn_mfma_f32_16x16x32_bf16(
            av[ii][ks], bv[QJ * 2 + jj][ks], acc[QI * 4 + ii][QJ * 2 + jj], 0, 0, 0);
  __builtin_amdgcn_s_setprio(0);
}

__global__ __launch_bounds__(512, 2) void gemm256(
    const uint16_t* __restrict__ Ag, const uint16_t* __restrict__ Bg,
    float* __restrict__ C)
{
  __shared__ bf16 sA[2][256 * 64];   // 64 KB
  __shared__ bf16 sB[2][256 * 64];   // 64 KB

  const int tid  = threadIdx.x;
  const int lane = tid & 63;
  const int w    = tid >> 6;        // 0..7
  const int wm2  = w >> 2;          // 0..1 : M half
  const int wn4  = w & 3;           // 0..3 : N quarter
  const int r15  = lane & 15;
  const int q4   = lane >> 4;
  const int abase = wm2 * 128;
  const int bbase = wn4 * 64;

  // T1: bijective XCD chunking. 2528 blocks = 8 XCDs x 316; each XCD works
  // one m-tile at a time across n (A-panel stays hot in its L2).
  const int id = blockIdx.x;
  const int rb = id >> 3;
  const int mt = (id & 7) * 4 + rb / NTIL;
  const int nt = rb % NTIL;
  const int m0 = mt * 256;
  const int n0 = nt * 256;

  bf16x8 av[4][2], bv[4][2];
  f32x4 acc[8][4] = {};

  // ---- prologue: tile0 fully + tile1 U1..U3, then counted wait -------------
  stage_unit<0>(Ag, m0, 0,  &sA[0][0], w, lane, MB_ - 1);   // U1(0)
  stage_unit<2>(Bg, n0, 0,  &sB[0][0], w, lane, NPAD - 1);  // U2(0)
  stage_unit<1>(Ag, m0, 0,  &sA[0][0], w, lane, MB_ - 1);   // U3(0)
  stage_unit<3>(Bg, n0, 0,  &sB[0][0], w, lane, NPAD - 1);  // U4(0)
  stage_unit<0>(Ag, m0, 64, &sA[1][0], w, lane, MB_ - 1);   // U1(1)
  stage_unit<2>(Bg, n0, 64, &sB[1][0], w, lane, NPAD - 1);  // U2(1)
  stage_unit<1>(Ag, m0, 64, &sA[1][0], w, lane, MB_ - 1);   // U3(1)
  asm volatile("s_waitcnt vmcnt(6)" ::: "memory");          // tile0 landed
  __builtin_amdgcn_s_barrier();

  for (int t = 0; t < NT; ++t) {
    bf16* At  = &sA[t & 1][0];
    bf16* Bt  = &sB[t & 1][0];
    bf16* Bn1 = &sB[(t + 1) & 1][0];
    const int kb1 = (t + 1) * 64, kb2 = (t + 2) * 64;

    // ---- phase 1: compute (0,0); stage U4(t+1)
    #pragma unroll
    for (int ii = 0; ii < 4; ++ii)
      #pragma unroll
      for (int ks = 0; ks < 2; ++ks)
        av[ii][ks] = ldsread(At, abase + ii * 16 + r15, ks * 4 + q4);
    #pragma unroll
    for (int jj = 0; jj < 2; ++jj)
      #pragma unroll
      for (int ks = 0; ks < 2; ++ks)
        bv[jj][ks] = ldsread(Bt, bbase + jj * 16 + r15, ks * 4 + q4);
    if (t + 1 < NT) stage_unit<3>(Bg, n0, kb1, Bn1, w, lane, NPAD - 1);
    phase_mfma<0, 0>(acc, av, bv);
    __builtin_amdgcn_s_barrier();

    // ---- phase 2: compute (0,1); stage U1(t+2) into current buf (A-low free)
    #pragma unroll
    for (int jj = 2; jj < 4; ++jj)
      #pragma unroll
      for (int ks = 0; ks < 2; ++ks)
        bv[jj][ks] = ldsread(Bt, bbase + jj * 16 + r15, ks * 4 + q4);
    if (t + 2 < NT) stage_unit<0>(Ag, m0, kb2, At, w, lane, MB_ - 1);
    phase_mfma<0, 1>(acc, av, bv);
    __builtin_amdgcn_s_barrier();

    // ---- phase 3: compute (1,0); stage U2(t+2) (B-low free)
    #pragma unroll
    for (int ii = 0; ii < 4; ++ii)
      #pragma unroll
      for (int ks = 0; ks < 2; ++ks)
        av[ii][ks] = ldsread(At, abase + 64 + ii * 16 + r15, ks * 4 + q4);
    if (t + 2 < NT) stage_unit<2>(Bg, n0, kb2, Bt, w, lane, NPAD - 1);
    phase_mfma<1, 0>(acc, av, bv);
    __builtin_amdgcn_s_barrier();

    // ---- phase 4: compute (1,1); stage U3(t+2) (A-high free); counted wait
    if (t + 2 < NT) stage_unit<1>(Ag, m0, kb2, At, w, lane, MB_ - 1);
    phase_mfma<1, 1>(acc, av, bv);
    if (t + 2 < NT)      { asm volatile("s_waitcnt vmcnt(6)" ::: "memory"); }
    else if (t + 1 < NT) { asm volatile("s_waitcnt vmcnt(0)" ::: "memory"); }
    __builtin_amdgcn_s_barrier();
  }

  // ---- epilogue: C write (row = ..+q4*4+rr, col = ..+r15) ------------------
  #pragma unroll
  for (int i = 0; i < 8; ++i) {
    const int row = m0 + abase + i * 16 + q4 * 4;
    #pragma unroll
    for (int j = 0; j < 4; ++j) {
      const int col = n0 + bbase + j * 16 + r15;
      if (col < NOX) {
        #pragma unroll
        for (int rr = 0; rr < 4; ++rr)
          C[(size_t)(row + rr) * NOX + col] = acc[i][j][rr];
      }
    }
  }
}

// ---------------------------------------------------------------------------
// Softmax + library-size scale, in place on logits. One block per row.
// ---------------------------------------------------------------------------
__global__ __launch_bounds__(256) void softmax_scale(
    float* __restrict__ io, const float* __restrict__ lls)
{
  const int m = blockIdx.x;
  float* row = io + (size_t)m * NOX;
  float4* row4 = (float4*)row;
  const int t = threadIdx.x;

  float mx = -1e30f, sm = 0.f;
  for (int i = t; i < NOX / 4; i += 256) {
    float4 v = row4[i];
    float lm = fmaxf(fmaxf(v.x, v.y), fmaxf(v.z, v.w));
    if (lm > mx) { sm *= __expf(mx - lm); mx = lm; }
    sm += __expf(v.x - mx) + __expf(v.y - mx) + __expf(v.z - mx) + __expf(v.w - mx);
  }
  // wave-64 reduce
  #pragma unroll
  for (int off = 32; off > 0; off >>= 1) {
    float mo = __shfl_down(mx, off);
    float so = __shfl_down(sm, off);
    float nm = fmaxf(mx, mo);
    sm = sm * __expf(mx - nm) + so * __expf(mo - nm);
    mx = nm;
  }
  __shared__ float red_m[4], red_s[4], fin[2];
  const int lane = t & 63, wv = t >> 6;
  if (lane == 0) { red_m[wv] = mx; red_s[wv] = sm; }
  __syncthreads();
  if (t == 0) {
    float M = red_m[0], S = red_s[0];
    #pragma unroll
    for (int i = 1; i < 4; ++i) {
      float nm = fmaxf(M, red_m[i]);
      S = S * __expf(M - nm) + red_s[i] * __expf(red_m[i] - nm);
      M = nm;
    }
    fin[0] = M;
    fin[1] = __expf(lls[m]) / S;
  }
  __syncthreads();
  const float M = fin[0], Cf = fin[1];
  for (int i = t; i < NOX / 4; i += 256) {
    float4 v = row4[i];
    v.x = __expf(v.x - M) * Cf;
    v.y = __expf(v.y - M) * Cf;
    v.z = __expf(v.z - M) * Cf;
    v.w = __expf(v.w - M) * Cf;
    row4[i] = v;
  }
}

// ---------------------------------------------------------------------------
extern "C" void kernel_launch(void* const* d_in, const int* in_sizes, int n_in,
                              void* d_out, int out_size, void* d_ws, size_t ws_size,
                              hipStream_t stream) {
  const float* z    = (const float*)d_in[0];  // (8192, 2304)
  const float* lls  = (const float*)d_in[1];  // (8192, 1)
  const float* cat  = (const float*)d_in[2];  // (8192, 32)
  const float* mask = (const float*)d_in[3];  // (2048, 20000)
  const float* am   = (const float*)d_in[4];  // (256, 20000)
  const float* Wm   = (const float*)d_in[5];  // (2048, 20000)
  const float* Wa   = (const float*)d_in[6];  // (256, 20000)
  const float* Wc   = (const float*)d_in[7];  // (32, 20000)
  float* out = (float*)d_out;                 // (8192, 20000)

  uint16_t* zc  = (uint16_t*)d_ws;                       // 8192*2368*2  = 38.8 MB
  uint16_t* wct = zc + (size_t)MB_ * KP;                 // 20096*2368*2 = 95.2 MB

  build_zc<<<(MB_ * (KP / 8)) / 256, 256, 0, stream>>>(z, cat, (uint4*)zc);
  build_wct<<<dim3(NPAD / 64, KP / 64), 256, 0, stream>>>(Wm, mask, Wa, am, Wc, wct);
  gemm256<<<MTIL * NTIL, 512, 0, stream>>>(zc, wct, out);
  softmax_scale<<<MB_, 256, 0, stream>>>(out, lls);
}

// Round 2
// 2113.824 us; speedup vs baseline: 1.1027x; 1.0032x over previous
//
#include <hip/hip_runtime.h>
#include <cstdint>
#include <cstddef>

// Problem constants
#define MB_   8192            // batch
#define NPX   2048            // masked features
#define NAX   256             // addon
#define NCX   32              // covariates
#define NOX   20000           // output features
#define KTOT  2336            // 2048+256+32
#define KP    2368            // K padded to multiple of 64 (37 tiles)
#define NPAD  20096           // N rows materialized in wct (314*64)
#define NT    37              // K tiles (KP/64)
#define MTIL  32              // 8192/256
#define NTIL  79              // ceil(20000/256) -> 20224 logical cols

typedef __bf16 bf16;
typedef bf16  bf16x8 __attribute__((ext_vector_type(8)));
typedef float f32x4  __attribute__((ext_vector_type(4)));

__device__ __forceinline__ uint16_t f2bf(float f) {
  union { float f; uint32_t u; } v; v.f = f;
  uint32_t u = v.u;
  return (uint16_t)((u + 0x7FFFu + ((u >> 16) & 1u)) >> 16);  // RNE
}

__device__ __forceinline__ void gl_lds16(const void* g, void* l) {
  __builtin_amdgcn_global_load_lds(
      (const __attribute__((address_space(1))) void*)g,
      (__attribute__((address_space(3))) void*)l,
      16, 0, 0);
}

#define WAIT_LGKM0() do { \
  asm volatile("s_waitcnt lgkmcnt(0)" ::: "memory"); \
  __builtin_amdgcn_sched_barrier(0); } while (0)
#define WAIT_VM(n) do { \
  asm volatile("s_waitcnt vmcnt(" #n ")" ::: "memory"); \
  __builtin_amdgcn_sched_barrier(0); } while (0)

// ---------------------------------------------------------------------------
// Pre-pass 1: zc[m][k] = bf16( k<2304 ? z[m][k] : (k<2336 ? cat[m][k-2304] : 0) )
// ---------------------------------------------------------------------------
__global__ __launch_bounds__(256) void build_zc(
    const float* __restrict__ z, const float* __restrict__ cat,
    uint4* __restrict__ zc)
{
  int t = blockIdx.x * 256 + threadIdx.x;     // exactly 8192*296 threads
  int m = t / 296, kb = t % 296;
  union { uint16_t u[8]; uint4 v; } U;
  if (kb < 288) {
    const float* p = z + (size_t)m * (NPX + NAX) + kb * 8;
    #pragma unroll
    for (int j = 0; j < 8; ++j) U.u[j] = f2bf(p[j]);
  } else if (kb < 292) {
    const float* p = cat + (size_t)m * NCX + (kb - 288) * 8;
    #pragma unroll
    for (int j = 0; j < 8; ++j) U.u[j] = f2bf(p[j]);
  } else {
    #pragma unroll
    for (int j = 0; j < 8; ++j) U.u[j] = 0;
  }
  zc[t] = U.v;
}

// ---------------------------------------------------------------------------
// Pre-pass 2: WcT[n][k] = bf16 of combined weight, transposed via LDS tiles.
// ---------------------------------------------------------------------------
__device__ __forceinline__ float wval(int k, int n,
    const float* __restrict__ Wm, const float* __restrict__ Mk,
    const float* __restrict__ Wa, const float* __restrict__ Am,
    const float* __restrict__ Wc)
{
  if (k < NPX)        return Wm[(size_t)k * NOX + n] * Mk[(size_t)k * NOX + n];
  if (k < NPX + NAX)  { int kk = k - NPX;       return Wa[(size_t)kk * NOX + n] * Am[(size_t)kk * NOX + n]; }
  if (k < KTOT)       { int kk = k - NPX - NAX; return Wc[(size_t)kk * NOX + n]; }
  return 0.f;
}

__global__ __launch_bounds__(256) void build_wct(
    const float* __restrict__ Wm, const float* __restrict__ Mk,
    const float* __restrict__ Wa, const float* __restrict__ Am,
    const float* __restrict__ Wc, uint16_t* __restrict__ wct)
{
  __shared__ float tile[64][65];
  const int n0 = blockIdx.x * 64;   // 314 tiles (NPAD/64)
  const int k0 = blockIdx.y * 64;   // 37 tiles  (KP/64)
  const int t = threadIdx.x;
  {
    const int nl = t & 63, kl0 = t >> 6;
    #pragma unroll
    for (int p = 0; p < 16; ++p) {
      int kl = p * 4 + kl0;
      int k = k0 + kl, n = n0 + nl;
      float v = 0.f;
      if (n < NOX) v = wval(k, n, Wm, Mk, Wa, Am, Wc);
      tile[kl][nl] = v;
    }
  }
  __syncthreads();
  {
    const int kl = t & 63, nl0 = t >> 6;
    #pragma unroll
    for (int p = 0; p < 16; ++p) {
      int nl = p * 4 + nl0;
      int n = n0 + nl;                       // n < 20096 always
      wct[(size_t)n * KP + k0 + kl] = f2bf(tile[kl][nl]);
    }
  }
}

// ---------------------------------------------------------------------------
// GEMM, 256x256 tile / BK=64 / 8 waves (2M x 4N) / 8-phase schedule.
//   T1 XCD-chunked block swizzle, T2 (row&7) chunk-XOR LDS swizzle
//   (linear LDS dest + inverse-swizzled global source + swizzled ds_read),
//   T3+T4 4 phases per K-tile with counted vmcnt(6) once per tile,
//   T5 setprio around MFMA clusters.
// Round-2: all staging addresses precomputed (uint32 element offsets, one
// v_add per load in the loop); sched_barrier(0) after every inline waitcnt
// (rule #18 — keeps hipcc from hoisting MFMA past the lgkmcnt / reshuffling
// the phase interior).
// Staging units per K-tile (16 KB each, 2 gl_lds16 per thread):
//   A0 = A rows {0-63,128-191}   A1 = A rows {64-127,192-255}
//   B0 = B rows {q*64+[0,32)}    B1 = B rows {q*64+[32,64)}
// Steady state during tile t:
//   ph1: B1(t+1) -> buf^1 ; ph2: A0(t+2) -> buf ; ph3: B0(t+2) ; ph4: A1(t+2)
//   then vmcnt(6) guarantees everything through B1(t+1) landed.
// ---------------------------------------------------------------------------
__device__ __forceinline__ int umap(int mode, int idx) {
  if (mode == 0) return idx + (idx & 64);            // A-low
  if (mode == 1) return 64 + idx + (idx & 64);       // A-high
  if (mode == 2) return ((idx >> 5) << 6) | (idx & 31);        // B-low
  return ((idx >> 5) << 6) | 32 | (idx & 31);                  // B-high
}

__device__ __forceinline__ bf16x8 ldsread(const bf16* base, int row, int ck) {
  // logical (row, chunk ck) lives at storage chunk ck ^ (row&7)
  return *(const bf16x8*)&base[row * 64 + ((ck ^ (row & 7)) << 3)];
}

template <int QI, int QJ>
__device__ __forceinline__ void phase_mfma(f32x4 (&acc)[8][4],
    const bf16x8 (&av)[4][2], const bf16x8 (&bv)[4][2])
{
  __builtin_amdgcn_s_barrier();
  WAIT_LGKM0();
  __builtin_amdgcn_s_setprio(1);
  #pragma unroll
  for (int ks = 0; ks < 2; ++ks)
    #pragma unroll
    for (int ii = 0; ii < 4; ++ii)
      #pragma unroll
      for (int jj = 0; jj < 2; ++jj)
        acc[QI * 4 + ii][QJ * 2 + jj] = __builtin_amdgcn_mfma_f32_16x16x32_bf16(
            av[ii][ks], bv[QJ * 2 + jj][ks], acc[QI * 4 + ii][QJ * 2 + jj], 0, 0, 0);
  __builtin_amdgcn_s_setprio(0);
}

__global__ __launch_bounds__(512, 2) void gemm256(
    const uint16_t* __restrict__ Ag, const uint16_t* __restrict__ Bg,
    float* __restrict__ C)
{
  __shared__ bf16 sA[2][256 * 64];   // 64 KB
  __shared__ bf16 sB[2][256 * 64];   // 64 KB

  const int tid  = threadIdx.x;
  const int lane = tid & 63;
  const int w    = tid >> 6;        // 0..7
  const int wm2  = w >> 2;          // 0..1 : M half
  const int wn4  = w & 3;           // 0..3 : N quarter
  const int r15  = lane & 15;
  const int q4   = lane >> 4;
  const int abase = wm2 * 128;
  const int bbase = wn4 * 64;

  // T1: bijective XCD chunking. 2528 blocks = 8 XCDs x 316; each XCD works
  // one m-tile at a time across n (A-panel stays hot in its L2).
  const int id = blockIdx.x;
  const int rb = id >> 3;
  const int mt = (id & 7) * 4 + rb / NTIL;
  const int nt = rb % NTIL;
  const int m0 = mt * 256;
  const int n0 = nt * 256;

  // ---- precomputed staging state (loop-invariant) --------------------------
  // ga[md][l]/gb[md][l]: uint32 element offsets into Ag/Bg (add kb per use).
  // la/lb: LDS element offsets (row*64) relative to the buffer base.
  uint32_t ga[2][2], gb[2][2];
  int      la[2][2], lb[2][2];
  {
    const int cswz = (((lane & 7) ^ (lane >> 3)) << 3);
    const int lr   = lane >> 3;
    #pragma unroll
    for (int md = 0; md < 2; ++md)
      #pragma unroll
      for (int l = 0; l < 2; ++l) {
        const int idx0 = (w * 2 + l) * 8;
        const int rA = umap(md, idx0);
        const int rB = umap(md + 2, idx0);
        int grA = m0 + rA + lr; if (grA > MB_ - 1)  grA = MB_ - 1;
        int grB = n0 + rB + lr; if (grB > NPAD - 1) grB = NPAD - 1;
        ga[md][l] = (uint32_t)grA * KP + cswz;
        gb[md][l] = (uint32_t)grB * KP + cswz;
        la[md][l] = rA * 64;
        lb[md][l] = rB * 64;
      }
  }

  bf16x8 av[4][2], bv[4][2];
  f32x4 acc[8][4] = {};

  // ---- prologue: tile0 fully + tile1 A0,B0,A1, then counted wait -----------
  #define STAGE_A(md, dst, kb) do { \
    gl_lds16(Ag + ga[md][0] + (kb), (dst) + la[md][0]); \
    gl_lds16(Ag + ga[md][1] + (kb), (dst) + la[md][1]); } while (0)
  #define STAGE_B(md, dst, kb) do { \
    gl_lds16(Bg + gb[md][0] + (kb), (dst) + lb[md][0]); \
    gl_lds16(Bg + gb[md][1] + (kb), (dst) + lb[md][1]); } while (0)

  STAGE_A(0, &sA[0][0], 0);  STAGE_B(0, &sB[0][0], 0);
  STAGE_A(1, &sA[0][0], 0);  STAGE_B(1, &sB[0][0], 0);
  STAGE_A(0, &sA[1][0], 64); STAGE_B(0, &sB[1][0], 64);
  STAGE_A(1, &sA[1][0], 64);
  WAIT_VM(6);                                   // tile0 landed
  __builtin_amdgcn_s_barrier();

  for (int t = 0; t < NT; ++t) {
    bf16* At  = &sA[t & 1][0];
    bf16* Bt  = &sB[t & 1][0];
    bf16* Bn1 = &sB[(t + 1) & 1][0];
    const int kb1 = (t + 1) * 64, kb2 = (t + 2) * 64;

    // ---- phase 1: compute (0,0); stage B1(t+1)
    #pragma unroll
    for (int ii = 0; ii < 4; ++ii)
      #pragma unroll
      for (int ks = 0; ks < 2; ++ks)
        av[ii][ks] = ldsread(At, abase + ii * 16 + r15, ks * 4 + q4);
    #pragma unroll
    for (int jj = 0; jj < 2; ++jj)
      #pragma unroll
      for (int ks = 0; ks < 2; ++ks)
        bv[jj][ks] = ldsread(Bt, bbase + jj * 16 + r15, ks * 4 + q4);
    if (t + 1 < NT) STAGE_B(1, Bn1, kb1);
    phase_mfma<0, 0>(acc, av, bv);
    __builtin_amdgcn_s_barrier();

    // ---- phase 2: compute (0,1); stage A0(t+2) into current buf (A-low free)
    #pragma unroll
    for (int jj = 2; jj < 4; ++jj)
      #pragma unroll
      for (int ks = 0; ks < 2; ++ks)
        bv[jj][ks] = ldsread(Bt, bbase + jj * 16 + r15, ks * 4 + q4);
    if (t + 2 < NT) STAGE_A(0, At, kb2);
    phase_mfma<0, 1>(acc, av, bv);
    __builtin_amdgcn_s_barrier();

    // ---- phase 3: compute (1,0); stage B0(t+2) (B-low free)
    #pragma unroll
    for (int ii = 0; ii < 4; ++ii)
      #pragma unroll
      for (int ks = 0; ks < 2; ++ks)
        av[ii][ks] = ldsread(At, abase + 64 + ii * 16 + r15, ks * 4 + q4);
    if (t + 2 < NT) STAGE_B(0, Bt, kb2);
    phase_mfma<1, 0>(acc, av, bv);
    __builtin_amdgcn_s_barrier();

    // ---- phase 4: compute (1,1); stage A1(t+2) (A-high free); counted wait
    if (t + 2 < NT) STAGE_A(1, At, kb2);
    phase_mfma<1, 1>(acc, av, bv);
    if (t + 2 < NT)      { WAIT_VM(6); }
    else if (t + 1 < NT) { WAIT_VM(0); }
    __builtin_amdgcn_s_barrier();
  }

  // ---- epilogue: C write (row = ..+q4*4+rr, col = ..+r15) ------------------
  #pragma unroll
  for (int i = 0; i < 8; ++i) {
    const int row = m0 + abase + i * 16 + q4 * 4;
    #pragma unroll
    for (int j = 0; j < 4; ++j) {
      const int col = n0 + bbase + j * 16 + r15;
      if (col < NOX) {
        #pragma unroll
        for (int rr = 0; rr < 4; ++rr)
          C[(size_t)(row + rr) * NOX + col] = acc[i][j][rr];
      }
    }
  }
}

// ---------------------------------------------------------------------------
// Softmax + library-size scale, in place on logits. One block per row.
// Round-2: row staged in LDS (80 KB, 2 blocks/CU) -> single global read +
// single global write instead of read/read/write.
// ---------------------------------------------------------------------------
__global__ __launch_bounds__(256) void softmax_scale(
    float* __restrict__ io, const float* __restrict__ lls)
{
  __shared__ float srow[NOX];          // 80000 B
  __shared__ float red_m[4], red_s[4], fin[2];
  const int m = blockIdx.x;
  float* row = io + (size_t)m * NOX;
  float4* row4 = (float4*)row;
  float4* srow4 = (float4*)srow;
  const int t = threadIdx.x;

  float mx = -1e30f, sm = 0.f;
  for (int i = t; i < NOX / 4; i += 256) {
    float4 v = row4[i];
    srow4[i] = v;
    float lm = fmaxf(fmaxf(v.x, v.y), fmaxf(v.z, v.w));
    if (lm > mx) { sm *= __expf(mx - lm); mx = lm; }
    sm += __expf(v.x - mx) + __expf(v.y - mx) + __expf(v.z - mx) + __expf(v.w - mx);
  }
  // wave-64 reduce
  #pragma unroll
  for (int off = 32; off > 0; off >>= 1) {
    float mo = __shfl_down(mx, off);
    float so = __shfl_down(sm, off);
    float nm = fmaxf(mx, mo);
    sm = sm * __expf(mx - nm) + so * __expf(mo - nm);
    mx = nm;
  }
  const int lane = t & 63, wv = t >> 6;
  if (lane == 0) { red_m[wv] = mx; red_s[wv] = sm; }
  __syncthreads();
  if (t == 0) {
    float M = red_m[0], S = red_s[0];
    #pragma unroll
    for (int i = 1; i < 4; ++i) {
      float nm = fmaxf(M, red_m[i]);
      S = S * __expf(M - nm) + red_s[i] * __expf(red_m[i] - nm);
      M = nm;
    }
    fin[0] = M;
    fin[1] = __expf(lls[m]) / S;
  }
  __syncthreads();
  const float M = fin[0], Cf = fin[1];
  for (int i = t; i < NOX / 4; i += 256) {
    float4 v = srow4[i];
    v.x = __expf(v.x - M) * Cf;
    v.y = __expf(v.y - M) * Cf;
    v.z = __expf(v.z - M) * Cf;
    v.w = __expf(v.w - M) * Cf;
    row4[i] = v;
  }
}

// ---------------------------------------------------------------------------
extern "C" void kernel_launch(void* const* d_in, const int* in_sizes, int n_in,
                              void* d_out, int out_size, void* d_ws, size_t ws_size,
                              hipStream_t stream) {
  const float* z    = (const float*)d_in[0];  // (8192, 2304)
  const float* lls  = (const float*)d_in[1];  // (8192, 1)
  const float* cat  = (const float*)d_in[2];  // (8192, 32)
  const float* mask = (const float*)d_in[3];  // (2048, 20000)
  const float* am   = (const float*)d_in[4];  // (256, 20000)
  const float* Wm   = (const float*)d_in[5];  // (2048, 20000)
  const float* Wa   = (const float*)d_in[6];  // (256, 20000)
  const float* Wc   = (const float*)d_in[7];  // (32, 20000)
  float* out = (float*)d_out;                 // (8192, 20000)

  uint16_t* zc  = (uint16_t*)d_ws;                       // 8192*2368*2  = 38.8 MB
  uint16_t* wct = zc + (size_t)MB_ * KP;                 // 20096*2368*2 = 95.2 MB

  build_zc<<<(MB_ * (KP / 8)) / 256, 256, 0, stream>>>(z, cat, (uint4*)zc);
  build_wct<<<dim3(NPAD / 64, KP / 64), 256, 0, stream>>>(Wm, mask, Wa, am, Wc, wct);
  gemm256<<<MTIL * NTIL, 512, 0, stream>>>(zc, wct, out);
  softmax_scale<<<MB_, 256, 0, stream>>>(out, lls);
}